// Round 2
// baseline (1106.292 us; speedup 1.0000x reference)
//
#include <hip/hip_runtime.h>
#include <math.h>

#define NN 50000
#define NE 800000

// ---------------------------------------------------------------- utilities
__device__ inline float wave_sum(float v) {
#pragma unroll
  for (int off = 32; off >= 1; off >>= 1) v += __shfl_xor(v, off, 64);
  return v;
}

// ---------------------------------------------------------------- graph prep
__global__ __launch_bounds__(256) void init_kernel(int* __restrict__ deg,
                                                   int* __restrict__ cursor, int n) {
  int i = blockIdx.x * 256 + threadIdx.x;
  if (i < n) { deg[i] = 1; cursor[i] = 0; }  // deg starts at 1 (self-loop)
}

__global__ __launch_bounds__(256) void deg_kernel(const int* __restrict__ ei,
                                                  int* __restrict__ deg) {
  int e = blockIdx.x * 256 + threadIdx.x;
  if (e < NE) atomicAdd(&deg[ei[NE + e]], 1);  // dst row of edge_index
}

__global__ __launch_bounds__(256) void dinv_kernel(const int* __restrict__ deg,
                                                   float* __restrict__ dinv, int n) {
  int i = blockIdx.x * 256 + threadIdx.x;
  if (i < n) dinv[i] = rsqrtf((float)deg[i]);  // deg >= 1 always
}

// single-block exclusive scan of deg -> offs[0..n], offs[n] = total
__global__ __launch_bounds__(256) void scan_kernel(const int* __restrict__ cnt,
                                                   int* __restrict__ offs, int n) {
  __shared__ int buf0[256], buf1[256];
  int tid = threadIdx.x;
  int per = (n + 255) >> 8;
  int start = tid * per;
  int end = min(start + per, n);
  int s = 0;
  for (int i = start; i < end; ++i) s += cnt[i];
  buf0[tid] = s;
  __syncthreads();
  int* src = buf0;
  int* dst = buf1;
#pragma unroll
  for (int off = 1; off < 256; off <<= 1) {
    int v = src[tid];
    if (tid >= off) v += src[tid - off];
    dst[tid] = v;
    __syncthreads();
    int* t = src; src = dst; dst = t;
  }
  int run = (tid == 0) ? 0 : src[tid - 1];
  for (int i = start; i < end; ++i) { offs[i] = run; run += cnt[i]; }
  if (end == n) offs[n] = run;
}

__global__ __launch_bounds__(256) void scatter_kernel(const int* __restrict__ ei,
                                                      const int* __restrict__ offs,
                                                      int* __restrict__ cursor,
                                                      int* __restrict__ csr) {
  int e = blockIdx.x * 256 + threadIdx.x;
  if (e >= NE + NN) return;
  int s, d;
  if (e < NE) { s = ei[e]; d = ei[NE + e]; }
  else        { s = e - NE; d = s; }           // self-loops
  int pos = atomicAdd(&cursor[d], 1);
  csr[offs[d] + pos] = s;
}

// ---------------------------------------------------------------- SGEMM
// C[M,N] = A[M,K] @ B[K,N]; EPI: 0 none, 1 bias+relu, 2 bias
// tile 128x64, BK=16, 256 threads, 8x4 microtile. Requires N%64==0, K%4==0.
#define BM 128
#define BN 64
#define BK 16
#define APAD 132  // BM+4 floats per k-row: 528B, 16B-aligned, bank-offset 4
#define BPAD 68   // BN+4

template <int EPI>
__global__ __launch_bounds__(256) void sgemm(const float* __restrict__ A,
                                             const float* __restrict__ B,
                                             const float* __restrict__ bias,
                                             float* __restrict__ C,
                                             int M, int N, int K) {
  __shared__ float As[BK][APAD];  // k-major: As[k][m]  (8448 B)
  __shared__ float Bs[BK][BPAD];  // Bs[k][n]           (4352 B)
  int tid = threadIdx.x;
  int tx = tid & 15;   // 16 groups * 4 cols  = 64 cols
  int ty = tid >> 4;   // 16 groups * 8 rows  = 128 rows
  int m0 = blockIdx.x * BM;
  int n0 = blockIdx.y * BN;

  float acc[8][4] = {};

  for (int k0 = 0; k0 < K; k0 += BK) {
    // A tile: 128 rows x 16 k = 512 float4s / 256 threads = 2 each, transposed store
#pragma unroll
    for (int i = 0; i < 2; ++i) {
      int idx = tid + i * 256;
      int row = idx >> 2;           // 0..127
      int kk4 = (idx & 3) << 2;     // 0,4,8,12
      int gm = m0 + row;
      int gk = k0 + kk4;
      float4 av = make_float4(0.f, 0.f, 0.f, 0.f);
      if (gm < M && gk + 3 < K) av = *(const float4*)&A[(size_t)gm * K + gk];
      As[kk4 + 0][row] = av.x;
      As[kk4 + 1][row] = av.y;
      As[kk4 + 2][row] = av.z;
      As[kk4 + 3][row] = av.w;
    }
    // B tile: 16 k x 64 cols = 256 float4s / 256 threads = 1 each
    {
      int kk = tid >> 4;
      int col = (tid & 15) << 2;
      int gk = k0 + kk;
      float4 bv = make_float4(0.f, 0.f, 0.f, 0.f);
      if (gk < K) bv = *(const float4*)&B[(size_t)gk * N + n0 + col];
      *(float4*)&Bs[kk][col] = bv;
    }
    __syncthreads();
#pragma unroll
    for (int kk = 0; kk < BK; ++kk) {
      float a[8], b[4];
      *(float4*)&a[0] = *(const float4*)&As[kk][ty << 3];
      *(float4*)&a[4] = *(const float4*)&As[kk][(ty << 3) + 4];
      *(float4*)&b[0] = *(const float4*)&Bs[kk][tx << 2];
#pragma unroll
      for (int i = 0; i < 8; ++i)
#pragma unroll
        for (int j = 0; j < 4; ++j) acc[i][j] += a[i] * b[j];
    }
    __syncthreads();
  }

  // epilogue
  float bv[4] = {0.f, 0.f, 0.f, 0.f};
  if (EPI) {
    float4 b4 = *(const float4*)&bias[n0 + (tx << 2)];
    bv[0] = b4.x; bv[1] = b4.y; bv[2] = b4.z; bv[3] = b4.w;
  }
#pragma unroll
  for (int i = 0; i < 8; ++i) {
    int gm = m0 + (ty << 3) + i;
    if (gm >= M) continue;
    float4 o;
    float* op = &o.x;
#pragma unroll
    for (int j = 0; j < 4; ++j) {
      float v = acc[i][j] + bv[j];
      if (EPI == 1) v = fmaxf(v, 0.f);
      op[j] = v;
    }
    *(float4*)&C[(size_t)gm * N + n0 + (tx << 2)] = o;
  }
}

// ---------------------------------------------------------------- aggregation
// out[n, col] = relu(dinv[n] * sum_{s in nbrs(n)} dinv[s]*xw[s,col] + bias[col])
template <int C>
__global__ __launch_bounds__(C) void agg_kernel(const float* __restrict__ xw,
                                                const int* __restrict__ offs,
                                                const int* __restrict__ csr,
                                                const float* __restrict__ dinv,
                                                const float* __restrict__ bias,
                                                float* __restrict__ out) {
  int node = blockIdx.x;
  int col = threadIdx.x;
  int beg = offs[node], end = offs[node + 1];
  float acc = 0.f;
  int j = beg;
  for (; j + 4 <= end; j += 4) {
    int s0 = csr[j], s1 = csr[j + 1], s2 = csr[j + 2], s3 = csr[j + 3];
    float d0 = dinv[s0], d1 = dinv[s1], d2 = dinv[s2], d3 = dinv[s3];
    float x0 = xw[(size_t)s0 * C + col];
    float x1 = xw[(size_t)s1 * C + col];
    float x2 = xw[(size_t)s2 * C + col];
    float x3 = xw[(size_t)s3 * C + col];
    acc += d0 * x0 + d1 * x1 + d2 * x2 + d3 * x3;
  }
  for (; j < end; ++j) {
    int s = csr[j];
    acc += dinv[s] * xw[(size_t)s * C + col];
  }
  float v = dinv[node] * acc + bias[col];
  out[(size_t)node * C + col] = fmaxf(v, 0.f);
}

// ---------------------------------------------------------------- row L2 norm
__global__ __launch_bounds__(128) void rownorm_kernel(const float* __restrict__ zi,
                                                      float* __restrict__ z) {
  int row = blockIdx.x;
  int t = threadIdx.x;
  float v = zi[(size_t)row * 128 + t];
  float ss = wave_sum(v * v);
  __shared__ float wsum[2];
  if ((t & 63) == 0) wsum[t >> 6] = ss;
  __syncthreads();
  float tot = wsum[0] + wsum[1];
  float rinv = 1.f / fmaxf(sqrtf(tot), 1e-12f);
  z[(size_t)row * 128 + t] = v * rinv;
}

// ---------------------------------------------------------------- classifier head
// out[row, 0..9] = softmax(c1[row, 0..511] @ W[512,10] + bias)
__global__ __launch_bounds__(256) void cls_kernel(const float* __restrict__ c1,
                                                  const float* __restrict__ W,
                                                  const float* __restrict__ bias,
                                                  float* __restrict__ out, int M) {
  __shared__ float Wt[10 * 512];  // transposed: Wt[c*512 + k]
  int tid = threadIdx.x;
  for (int i = tid; i < 5120; i += 256) Wt[i] = W[(i & 511) * 10 + (i >> 9)];
  __syncthreads();
  int wave = tid >> 6, lane = tid & 63;
  int row0 = blockIdx.x * 16 + wave * 4;
#pragma unroll 1
  for (int r = 0; r < 4; ++r) {
    int row = row0 + r;
    if (row >= M) continue;
    float acc[10] = {};
    const float* xr = c1 + (size_t)row * 512;
    for (int k = lane; k < 512; k += 64) {
      float xv = xr[k];
#pragma unroll
      for (int c = 0; c < 10; ++c) acc[c] += xv * Wt[c * 512 + k];
    }
#pragma unroll
    for (int c = 0; c < 10; ++c) acc[c] = wave_sum(acc[c]);
    float mx = -1e30f;
#pragma unroll
    for (int c = 0; c < 10; ++c) { acc[c] += bias[c]; mx = fmaxf(mx, acc[c]); }
    float sum = 0.f;
#pragma unroll
    for (int c = 0; c < 10; ++c) { acc[c] = expf(acc[c] - mx); sum += acc[c]; }
    float rs = 1.f / sum;
    if (lane < 10) out[(size_t)row * 10 + lane] = acc[lane] * rs;
  }
}

// ---------------------------------------------------------------- launch
extern "C" void kernel_launch(void* const* d_in, const int* in_sizes, int n_in,
                              void* d_out, int out_size, void* d_ws, size_t ws_size,
                              hipStream_t stream) {
  const float* x   = (const float*)d_in[0];
  const int*   ei  = (const int*)d_in[1];
  const float* W1  = (const float*)d_in[2];
  const float* b1  = (const float*)d_in[3];
  const float* W2  = (const float*)d_in[4];
  const float* b2  = (const float*)d_in[5];
  const float* Wi1 = (const float*)d_in[6];
  const float* bi1 = (const float*)d_in[7];
  const float* Wi2 = (const float*)d_in[8];
  const float* bi2 = (const float*)d_in[9];
  const float* Wc1 = (const float*)d_in[10];
  const float* bc1 = (const float*)d_in[11];
  const float* Wc2 = (const float*)d_in[12];
  const float* bc2 = (const float*)d_in[13];

  float* out_z = (float*)d_out;                      // [50000,128]
  float* out_c = (float*)d_out + (size_t)NN * 128;   // [50000,10]

  // workspace layout (aliased, strictly sequential lifetimes)
  char* ws = (char*)d_ws;
  size_t off = 0;
  auto alloc = [&](size_t bytes) {
    size_t r = off;
    off = (off + bytes + 255) & ~(size_t)255;
    return r;
  };
  int*   deg    = (int*)(ws + alloc((size_t)NN * 4));
  int*   cursor = (int*)(ws + alloc((size_t)NN * 4));
  int*   offs   = (int*)(ws + alloc((size_t)(NN + 1) * 4));
  float* dinv   = (float*)(ws + alloc((size_t)NN * 4));
  int*   csr    = (int*)(ws + alloc((size_t)(NE + NN) * 4));
  float* bufA   = (float*)(ws + alloc((size_t)NN * 256 * 4));  // xw -> hw2 -> zi
  float* bufB   = (float*)(ws + alloc((size_t)NN * 256 * 4));  // h1 -> h2
  float* bufD   = (float*)(ws + alloc((size_t)NN * 512 * 4));  // zi1 -> c1
  (void)ws_size; (void)in_sizes; (void)n_in; (void)out_size;

  const int M = NN;

  // graph prep
  init_kernel<<<(NN + 255) / 256, 256, 0, stream>>>(deg, cursor, NN);
  deg_kernel<<<(NE + 255) / 256, 256, 0, stream>>>(ei, deg);
  dinv_kernel<<<(NN + 255) / 256, 256, 0, stream>>>(deg, dinv, NN);
  scan_kernel<<<1, 256, 0, stream>>>(deg, offs, NN);
  scatter_kernel<<<(NE + NN + 255) / 256, 256, 0, stream>>>(ei, offs, cursor, csr);

  dim3 blk(256);
  // layer 1: xw = x @ W1   [M,500]@[500,256]
  sgemm<0><<<dim3((M + BM - 1) / BM, 256 / BN), blk, 0, stream>>>(x, W1, nullptr, bufA, M, 256, 500);
  agg_kernel<256><<<M, 256, 0, stream>>>(bufA, offs, csr, dinv, b1, bufB);  // h1
  // layer 2: hw2 = h1 @ W2   [M,256]@[256,128]
  sgemm<0><<<dim3((M + BM - 1) / BM, 128 / BN), blk, 0, stream>>>(bufB, W2, nullptr, bufA, M, 128, 256);
  agg_kernel<128><<<M, 128, 0, stream>>>(bufA, offs, csr, dinv, b2, bufB);  // h2
  // instance head: zi1 = relu(h2@Wi1+bi1); zi = zi1@Wi2+bi2; z = rownorm(zi)
  sgemm<1><<<dim3((M + BM - 1) / BM, 512 / BN), blk, 0, stream>>>(bufB, Wi1, bi1, bufD, M, 512, 128);
  sgemm<2><<<dim3((M + BM - 1) / BM, 128 / BN), blk, 0, stream>>>(bufD, Wi2, bi2, bufA, M, 128, 512);
  rownorm_kernel<<<M, 128, 0, stream>>>(bufA, out_z);
  // class head: c1 = relu(h2@Wc1+bc1); c = softmax(c1@Wc2+bc2)
  sgemm<1><<<dim3((M + BM - 1) / BM, 512 / BN), blk, 0, stream>>>(bufB, Wc1, bc1, bufD, M, 512, 128);
  cls_kernel<<<(M + 15) / 16, 256, 0, stream>>>(bufD, Wc2, bc2, out_c, M);
}

// Round 5
// 1013.438 us; speedup vs baseline: 1.0916x; 1.0916x over previous
//
#include <hip/hip_runtime.h>
#include <math.h>

#define NN 50000
#define NE 800000

typedef __attribute__((ext_vector_type(4))) float f32x4;
typedef __attribute__((ext_vector_type(8))) short s16x8;
typedef __attribute__((ext_vector_type(4))) short s16x4;

// ---------------------------------------------------------------- utilities
__device__ inline float wave_sum(float v) {
#pragma unroll
  for (int off = 32; off >= 1; off >>= 1) v += __shfl_xor(v, off, 64);
  return v;
}

// bijective XCD-chunked swizzle (m204): consecutive wgids within one XCD
__device__ inline int xcd_swizzle(int orig, int nwg) {
  int q = nwg >> 3, r = nwg & 7;
  int xcd = orig & 7, pos = orig >> 3;
  return (xcd < r ? xcd * (q + 1) : r * (q + 1) + (xcd - r) * q) + pos;
}

// fp32 -> bf16 RNE, and bf16 -> fp32
__device__ inline short f2bf(float f) {
  unsigned u = __float_as_uint(f);
  unsigned r = (u + 0x7fffu + ((u >> 16) & 1u)) >> 16;
  return (short)r;
}
__device__ inline float bf2f(short h) {
  return __uint_as_float(((unsigned)(unsigned short)h) << 16);
}

// ---------------------------------------------------------------- graph prep
__global__ __launch_bounds__(256) void init_kernel(int* __restrict__ deg,
                                                   int* __restrict__ cursor, int n) {
  int i = blockIdx.x * 256 + threadIdx.x;
  if (i < n) { deg[i] = 1; cursor[i] = 0; }  // deg starts at 1 (self-loop)
}

__global__ __launch_bounds__(256) void deg_kernel(const int* __restrict__ ei,
                                                  int* __restrict__ deg) {
  int e = blockIdx.x * 256 + threadIdx.x;
  if (e < NE) atomicAdd(&deg[ei[NE + e]], 1);  // dst row of edge_index
}

__global__ __launch_bounds__(256) void dinv_kernel(const int* __restrict__ deg,
                                                   float* __restrict__ dinv, int n) {
  int i = blockIdx.x * 256 + threadIdx.x;
  if (i < n) dinv[i] = rsqrtf((float)deg[i]);  // deg >= 1 always
}

// single-block exclusive scan of deg -> offs[0..n], offs[n] = total
__global__ __launch_bounds__(256) void scan_kernel(const int* __restrict__ cnt,
                                                   int* __restrict__ offs, int n) {
  __shared__ int buf0[256], buf1[256];
  int tid = threadIdx.x;
  int per = (n + 255) >> 8;
  int start = tid * per;
  int end = min(start + per, n);
  int s = 0;
  for (int i = start; i < end; ++i) s += cnt[i];
  buf0[tid] = s;
  __syncthreads();
  int* src = buf0;
  int* dst = buf1;
#pragma unroll
  for (int off = 1; off < 256; off <<= 1) {
    int v = src[tid];
    if (tid >= off) v += src[tid - off];
    dst[tid] = v;
    __syncthreads();
    int* t = src; src = dst; dst = t;
  }
  int run = (tid == 0) ? 0 : src[tid - 1];
  for (int i = start; i < end; ++i) { offs[i] = run; run += cnt[i]; }
  if (end == n) offs[n] = run;
}

__global__ __launch_bounds__(256) void scatter_kernel(const int* __restrict__ ei,
                                                      const int* __restrict__ offs,
                                                      int* __restrict__ cursor,
                                                      int* __restrict__ csr) {
  int e = blockIdx.x * 256 + threadIdx.x;
  if (e >= NE + NN) return;
  int s, d;
  if (e < NE) { s = ei[e]; d = ei[NE + e]; }
  else        { s = e - NE; d = s; }           // self-loops
  int pos = atomicAdd(&cursor[d], 1);
  csr[offs[d] + pos] = s;
}

// ---------------------------------------------------------------- MFMA GEMM
// C[M,N] = A[M,K] @ B[K,N] in split-bf16 (hi/lo, 3 MFMA products ~ fp32 precision).
// EPI: 0 none, 1 bias+relu, 2 bias. Tile 128x128, BK=64, 256 thr = 4 waves (2x2
// of 64x64). Requires N%128==0, K%4==0. LDS: [row][64] bf16, XOR-swizzled
// (kk ^ ((row&7)<<3)) so b128 fragment reads spread evenly over bank quads (T2).
// Fragment layouts (mfma_f32_16x16x32_bf16): A row=lane&15, k=(lane>>4)*8+j;
// B col=lane&15, same k; C/D col=lane&15, row=(lane>>4)*4+reg [m89].
template <int EPI>
__global__ __launch_bounds__(256, 2) void mfma_gemm(const float* __restrict__ A,
                                                    const float* __restrict__ B,
                                                    const float* __restrict__ bias,
                                                    float* __restrict__ C,
                                                    int M, int N, int K, int gn) {
  __shared__ short Ahi[128 * 64], Alo[128 * 64];  // 16 KB each
  __shared__ short Bhi[128 * 64], Blo[128 * 64];  // B stored [col][k]
  int tid = threadIdx.x;

  int wgid = xcd_swizzle(blockIdx.x, gridDim.x);
  int rb = wgid / gn;          // row block (col-fastest within XCD chunk)
  int cb = wgid - rb * gn;
  int m0 = rb * 128;
  int n0 = cb * 128;

  int wv = tid >> 6, lane = tid & 63;
  int wm = wv >> 1, wn = wv & 1;      // 2x2 wave grid, each 64x64
  int lrow = lane & 15, lblk = lane >> 4;

  // staging maps
  int asr = tid >> 4;          // A: sub-row 0..15 (row = p*16+asr)
  int ask = tid & 15;          // A: float4 slot (k = ask*4)
  int bcol = tid & 127;        // B: column
  int bkh = tid >> 7;          // B: k half (0..1)

  f32x4 acc[4][4] = {};

  int nt = (K + 63) >> 6;
  for (int t0 = 0; t0 < nt; ++t0) {
    int k0 = t0 << 6;
    __syncthreads();  // previous iter's reads done before overwrite
    // ---- stage A: 128 rows x 64 k, fp32 -> bf16 hi/lo in registers
#pragma unroll
    for (int p = 0; p < 8; ++p) {
      int row = p * 16 + asr;
      int gm = m0 + row;
      int gk = k0 + ask * 4;
      float4 v = make_float4(0.f, 0.f, 0.f, 0.f);
      if (gm < M && gk < K) v = *(const float4*)&A[(size_t)gm * K + gk];
      float fv[4] = {v.x, v.y, v.z, v.w};
      s16x4 h, l;
#pragma unroll
      for (int j = 0; j < 4; ++j) {
        short hh = f2bf(fv[j]);
        h[j] = hh;
        l[j] = f2bf(fv[j] - bf2f(hh));
      }
      int idx = row * 64 + ((ask * 4) ^ ((row & 7) << 3));
      *(s16x4*)&Ahi[idx] = h;
      *(s16x4*)&Alo[idx] = l;
    }
    // ---- stage B: [col][k] transposed, coalesced 4B reads along N
#pragma unroll
    for (int j = 0; j < 8; ++j) {
      s16x4 h, l;
#pragma unroll
      for (int i = 0; i < 4; ++i) {
        int kk = bkh * 32 + j * 4 + i;
        int gk = k0 + kk;
        float v = (gk < K) ? B[(size_t)gk * N + n0 + bcol] : 0.f;
        short hh = f2bf(v);
        h[i] = hh;
        l[i] = f2bf(v - bf2f(hh));
      }
      int kkb = bkh * 32 + j * 4;
      int idx = bcol * 64 + (kkb ^ ((bcol & 7) << 3));
      *(s16x4*)&Bhi[idx] = h;
      *(s16x4*)&Blo[idx] = l;
    }
    __syncthreads();
    // ---- compute: 2 k-steps of 32, 16 frag-pairs, 3 products each
#pragma unroll
    for (int s = 0; s < 2; ++s) {
      s16x8 ah[4], al[4], bh[4], bl[4];
      int kk = s * 32 + lblk * 8;
#pragma unroll
      for (int f = 0; f < 4; ++f) {
        int ra = wm * 64 + f * 16 + lrow;
        int ia = ra * 64 + (kk ^ ((ra & 7) << 3));
        ah[f] = *(const s16x8*)&Ahi[ia];
        al[f] = *(const s16x8*)&Alo[ia];
        int rbn = wn * 64 + f * 16 + lrow;
        int ib = rbn * 64 + (kk ^ ((rbn & 7) << 3));
        bh[f] = *(const s16x8*)&Bhi[ib];
        bl[f] = *(const s16x8*)&Blo[ib];
      }
#pragma unroll
      for (int i = 0; i < 4; ++i)
#pragma unroll
        for (int j = 0; j < 4; ++j) {
          acc[i][j] = __builtin_amdgcn_mfma_f32_16x16x32_bf16(ah[i], bh[j], acc[i][j], 0, 0, 0);
          acc[i][j] = __builtin_amdgcn_mfma_f32_16x16x32_bf16(ah[i], bl[j], acc[i][j], 0, 0, 0);
          acc[i][j] = __builtin_amdgcn_mfma_f32_16x16x32_bf16(al[i], bh[j], acc[i][j], 0, 0, 0);
        }
    }
  }

  // ---- epilogue: C/D layout col=lane&15, row=(lane>>4)*4+reg
#pragma unroll
  for (int i = 0; i < 4; ++i) {
    int crow0 = m0 + wm * 64 + i * 16 + lblk * 4;
#pragma unroll
    for (int j = 0; j < 4; ++j) {
      int ccol = n0 + wn * 64 + j * 16 + lrow;
      float bb = EPI ? bias[ccol] : 0.f;
#pragma unroll
      for (int r = 0; r < 4; ++r) {
        int crow = crow0 + r;
        if (crow < M) {
          float v = acc[i][j][r] + bb;
          if (EPI == 1) v = fmaxf(v, 0.f);
          C[(size_t)crow * N + ccol] = v;
        }
      }
    }
  }
}

// ---------------------------------------------------------------- aggregation
// out[n, :] = relu(dinv[n] * sum_{s in nbrs(n)} dinv[s]*xw[s,:] + bias)
// float4 per lane (16B, coalescing sweet spot); C/4 lanes per node.
template <int C>
__global__ __launch_bounds__(256) void agg_kernel(const float* __restrict__ xw,
                                                  const int* __restrict__ offs,
                                                  const int* __restrict__ csr,
                                                  const float* __restrict__ dinv,
                                                  const float* __restrict__ bias,
                                                  float* __restrict__ out) {
  constexpr int TPN = C / 4;       // threads per node (64 or 32)
  constexpr int NPB = 256 / TPN;   // nodes per block (4 or 8)
  int lane = threadIdx.x % TPN;
  int sub  = threadIdx.x / TPN;
  int node = blockIdx.x * NPB + sub;
  if (node >= NN) return;

  const float4* xw4 = (const float4*)xw;
  int beg = offs[node], end = offs[node + 1];
  float4 acc = make_float4(0.f, 0.f, 0.f, 0.f);
  int j = beg;
  for (; j + 2 <= end; j += 2) {
    int s0 = csr[j], s1 = csr[j + 1];
    float d0 = dinv[s0], d1 = dinv[s1];
    float4 v0 = xw4[(size_t)s0 * TPN + lane];
    float4 v1 = xw4[(size_t)s1 * TPN + lane];
    acc.x += d0 * v0.x + d1 * v1.x;
    acc.y += d0 * v0.y + d1 * v1.y;
    acc.z += d0 * v0.z + d1 * v1.z;
    acc.w += d0 * v0.w + d1 * v1.w;
  }
  if (j < end) {
    int s = csr[j];
    float d = dinv[s];
    float4 v = xw4[(size_t)s * TPN + lane];
    acc.x += d * v.x; acc.y += d * v.y; acc.z += d * v.z; acc.w += d * v.w;
  }
  float dn = dinv[node];
  float4 b = ((const float4*)bias)[lane];
  float4 o;
  o.x = fmaxf(dn * acc.x + b.x, 0.f);
  o.y = fmaxf(dn * acc.y + b.y, 0.f);
  o.z = fmaxf(dn * acc.z + b.z, 0.f);
  o.w = fmaxf(dn * acc.w + b.w, 0.f);
  ((float4*)out)[(size_t)node * TPN + lane] = o;
}

// ---------------------------------------------------------------- row L2 norm
__global__ __launch_bounds__(128) void rownorm_kernel(const float* __restrict__ zi,
                                                      float* __restrict__ z) {
  int row = blockIdx.x;
  int t = threadIdx.x;
  float v = zi[(size_t)row * 128 + t];
  float ss = wave_sum(v * v);
  __shared__ float wsum[2];
  if ((t & 63) == 0) wsum[t >> 6] = ss;
  __syncthreads();
  float tot = wsum[0] + wsum[1];
  float rinv = 1.f / fmaxf(sqrtf(tot), 1e-12f);
  z[(size_t)row * 128 + t] = v * rinv;
}

// ---------------------------------------------------------------- classifier head
// out[row, 0..9] = softmax(c1[row, 0..511] @ W[512,10] + bias)
__global__ __launch_bounds__(256) void cls_kernel(const float* __restrict__ c1,
                                                  const float* __restrict__ W,
                                                  const float* __restrict__ bias,
                                                  float* __restrict__ out, int M) {
  __shared__ float Wt[10 * 512];  // transposed: Wt[c*512 + k]
  int tid = threadIdx.x;
  for (int i = tid; i < 5120; i += 256) Wt[i] = W[(i & 511) * 10 + (i >> 9)];
  __syncthreads();
  int wave = tid >> 6, lane = tid & 63;
  int row0 = blockIdx.x * 16 + wave * 4;
#pragma unroll 1
  for (int r = 0; r < 4; ++r) {
    int row = row0 + r;
    if (row >= M) continue;
    float acc[10] = {};
    const float* xr = c1 + (size_t)row * 512;
    for (int k = lane; k < 512; k += 64) {
      float xv = xr[k];
#pragma unroll
      for (int c = 0; c < 10; ++c) acc[c] += xv * Wt[c * 512 + k];
    }
#pragma unroll
    for (int c = 0; c < 10; ++c) acc[c] = wave_sum(acc[c]);
    float mx = -1e30f;
#pragma unroll
    for (int c = 0; c < 10; ++c) { acc[c] += bias[c]; mx = fmaxf(mx, acc[c]); }
    float sum = 0.f;
#pragma unroll
    for (int c = 0; c < 10; ++c) { acc[c] = expf(acc[c] - mx); sum += acc[c]; }
    float rs = 1.f / sum;
    if (lane < 10) out[(size_t)row * 10 + lane] = acc[lane] * rs;
  }
}

// ---------------------------------------------------------------- launch
extern "C" void kernel_launch(void* const* d_in, const int* in_sizes, int n_in,
                              void* d_out, int out_size, void* d_ws, size_t ws_size,
                              hipStream_t stream) {
  const float* x   = (const float*)d_in[0];
  const int*   ei  = (const int*)d_in[1];
  const float* W1  = (const float*)d_in[2];
  const float* b1  = (const float*)d_in[3];
  const float* W2  = (const float*)d_in[4];
  const float* b2  = (const float*)d_in[5];
  const float* Wi1 = (const float*)d_in[6];
  const float* bi1 = (const float*)d_in[7];
  const float* Wi2 = (const float*)d_in[8];
  const float* bi2 = (const float*)d_in[9];
  const float* Wc1 = (const float*)d_in[10];
  const float* bc1 = (const float*)d_in[11];
  const float* Wc2 = (const float*)d_in[12];
  const float* bc2 = (const float*)d_in[13];

  float* out_z = (float*)d_out;                      // [50000,128]
  float* out_c = (float*)d_out + (size_t)NN * 128;   // [50000,10]

  // workspace layout (aliased, strictly sequential lifetimes)
  char* ws = (char*)d_ws;
  size_t off = 0;
  auto alloc = [&](size_t bytes) {
    size_t r = off;
    off = (off + bytes + 255) & ~(size_t)255;
    return r;
  };
  int*   deg    = (int*)(ws + alloc((size_t)NN * 4));
  int*   cursor = (int*)(ws + alloc((size_t)NN * 4));
  int*   offs   = (int*)(ws + alloc((size_t)(NN + 1) * 4));
  float* dinv   = (float*)(ws + alloc((size_t)NN * 4));
  int*   csr    = (int*)(ws + alloc((size_t)(NE + NN) * 4));
  float* bufA   = (float*)(ws + alloc((size_t)NN * 256 * 4));  // xw -> hw2 -> zi
  float* bufB   = (float*)(ws + alloc((size_t)NN * 256 * 4));  // h1 -> h2
  float* bufD   = (float*)(ws + alloc((size_t)NN * 512 * 4));  // zi1 -> c1
  (void)ws_size; (void)in_sizes; (void)n_in; (void)out_size;

  const int M = NN;
  const int gmb = (M + 127) / 128;  // 391 row blocks

  // graph prep
  init_kernel<<<(NN + 255) / 256, 256, 0, stream>>>(deg, cursor, NN);
  deg_kernel<<<(NE + 255) / 256, 256, 0, stream>>>(ei, deg);
  dinv_kernel<<<(NN + 255) / 256, 256, 0, stream>>>(deg, dinv, NN);
  scan_kernel<<<1, 256, 0, stream>>>(deg, offs, NN);
  scatter_kernel<<<(NE + NN + 255) / 256, 256, 0, stream>>>(ei, offs, cursor, csr);

  dim3 blk(256);
  // layer 1: xw = x @ W1   [M,500]@[500,256]
  mfma_gemm<0><<<gmb * 2, blk, 0, stream>>>(x, W1, nullptr, bufA, M, 256, 500, 2);
  agg_kernel<256><<<(NN + 3) / 4, 256, 0, stream>>>(bufA, offs, csr, dinv, b1, bufB);  // h1
  // layer 2: hw2 = h1 @ W2   [M,256]@[256,128]
  mfma_gemm<0><<<gmb * 1, blk, 0, stream>>>(bufB, W2, nullptr, bufA, M, 128, 256, 1);
  agg_kernel<128><<<(NN + 7) / 8, 256, 0, stream>>>(bufA, offs, csr, dinv, b2, bufB);  // h2
  // instance head: zi1 = relu(h2@Wi1+bi1); zi = zi1@Wi2+bi2; z = rownorm(zi)
  mfma_gemm<1><<<gmb * 4, blk, 0, stream>>>(bufB, Wi1, bi1, bufD, M, 512, 128, 4);
  mfma_gemm<2><<<gmb * 1, blk, 0, stream>>>(bufD, Wi2, bi2, bufA, M, 128, 512, 1);
  rownorm_kernel<<<M, 128, 0, stream>>>(bufA, out_z);
  // class head: c1 = relu(h2@Wc1+bc1); c = softmax(c1@Wc2+bc2)
  mfma_gemm<1><<<gmb * 4, blk, 0, stream>>>(bufB, Wc1, bc1, bufD, M, 512, 128, 4);
  cls_kernel<<<(M + 15) / 16, 256, 0, stream>>>(bufD, Wc2, bc2, out_c, M);
}

// Round 7
// 831.498 us; speedup vs baseline: 1.3305x; 1.2188x over previous
//
#include <hip/hip_runtime.h>
#include <math.h>

#define NN 50000
#define NE 800000

typedef __attribute__((ext_vector_type(4))) float f32x4;
typedef __attribute__((ext_vector_type(8))) short s16x8;
typedef __attribute__((ext_vector_type(4))) short s16x4;

// ---------------------------------------------------------------- utilities
__device__ inline float wave_sum(float v) {
#pragma unroll
  for (int off = 32; off >= 1; off >>= 1) v += __shfl_xor(v, off, 64);
  return v;
}

// bijective XCD-chunked swizzle (m204): consecutive wgids within one XCD
__device__ inline int xcd_swizzle(int orig, int nwg) {
  int q = nwg >> 3, r = nwg & 7;
  int xcd = orig & 7, pos = orig >> 3;
  return (xcd < r ? xcd * (q + 1) : r * (q + 1) + (xcd - r) * q) + pos;
}

// fp32 -> bf16 RNE, and bf16 -> fp32
__device__ inline short f2bf(float f) {
  unsigned u = __float_as_uint(f);
  unsigned r = (u + 0x7fffu + ((u >> 16) & 1u)) >> 16;
  return (short)r;
}
__device__ inline float bf2f(short h) {
  return __uint_as_float(((unsigned)(unsigned short)h) << 16);
}

// ---------------------------------------------------------------- graph prep
__global__ __launch_bounds__(256) void init_kernel(int* __restrict__ deg,
                                                   int* __restrict__ cursor, int n) {
  int i = blockIdx.x * 256 + threadIdx.x;
  if (i < n) { deg[i] = 1; cursor[i] = 0; }  // deg starts at 1 (self-loop)
}

__global__ __launch_bounds__(256) void deg_kernel(const int* __restrict__ ei,
                                                  int* __restrict__ deg) {
  int e = blockIdx.x * 256 + threadIdx.x;
  if (e < NE) atomicAdd(&deg[ei[NE + e]], 1);  // dst row of edge_index
}

__global__ __launch_bounds__(256) void dinv_kernel(const int* __restrict__ deg,
                                                   float* __restrict__ dinv, int n) {
  int i = blockIdx.x * 256 + threadIdx.x;
  if (i < n) dinv[i] = rsqrtf((float)deg[i]);  // deg >= 1 always
}

// single-block exclusive scan of deg -> offs[0..n], offs[n] = total
__global__ __launch_bounds__(256) void scan_kernel(const int* __restrict__ cnt,
                                                   int* __restrict__ offs, int n) {
  __shared__ int buf0[256], buf1[256];
  int tid = threadIdx.x;
  int per = (n + 255) >> 8;
  int start = tid * per;
  int end = min(start + per, n);
  int s = 0;
  for (int i = start; i < end; ++i) s += cnt[i];
  buf0[tid] = s;
  __syncthreads();
  int* src = buf0;
  int* dst = buf1;
#pragma unroll
  for (int off = 1; off < 256; off <<= 1) {
    int v = src[tid];
    if (tid >= off) v += src[tid - off];
    dst[tid] = v;
    __syncthreads();
    int* t = src; src = dst; dst = t;
  }
  int run = (tid == 0) ? 0 : src[tid - 1];
  for (int i = start; i < end; ++i) { offs[i] = run; run += cnt[i]; }
  if (end == n) offs[n] = run;
}

__global__ __launch_bounds__(256) void scatter_kernel(const int* __restrict__ ei,
                                                      const int* __restrict__ offs,
                                                      int* __restrict__ cursor,
                                                      int* __restrict__ csr) {
  int e = blockIdx.x * 256 + threadIdx.x;
  if (e >= NE + NN) return;
  int s, d;
  if (e < NE) { s = ei[e]; d = ei[NE + e]; }
  else        { s = e - NE; d = s; }           // self-loops
  int pos = atomicAdd(&cursor[d], 1);
  csr[offs[d] + pos] = s;
}

// ---------------------------------------------------------------- converters
// f32 [M][K] row-major -> bf16 hi/lo [M][KP], zero-padded to KP (KP%8==0)
__global__ __launch_bounds__(256) void convert_a(const float* __restrict__ in,
                                                 short* __restrict__ hi,
                                                 short* __restrict__ lo,
                                                 int M, int K, int KP) {
  int t = blockIdx.x * 256 + threadIdx.x;
  int perRow = KP >> 3;
  int row = t / perRow;
  if (row >= M) return;
  int k8 = (t - row * perRow) << 3;
  s16x8 h, l;
#pragma unroll
  for (int j = 0; j < 8; ++j) {
    int k = k8 + j;
    float v = (k < K) ? in[(size_t)row * K + k] : 0.f;
    short hh = f2bf(v);
    h[j] = hh;
    l[j] = f2bf(v - bf2f(hh));
  }
  *(s16x8*)&hi[(size_t)row * KP + k8] = h;
  *(s16x8*)&lo[(size_t)row * KP + k8] = l;
}

// weight f32 [K][N] -> TRANSPOSED bf16 hi/lo [N][KP], zero-padded
__global__ __launch_bounds__(256) void convert_w(const float* __restrict__ B,
                                                 short* __restrict__ hi,
                                                 short* __restrict__ lo,
                                                 int K, int N, int KP) {
  int t = blockIdx.x * 256 + threadIdx.x;
  int perRow = KP >> 3;
  int col = t / perRow;
  if (col >= N) return;
  int k8 = (t - col * perRow) << 3;
  s16x8 h, l;
#pragma unroll
  for (int j = 0; j < 8; ++j) {
    int k = k8 + j;
    float v = (k < K) ? B[(size_t)k * N + col] : 0.f;
    short hh = f2bf(v);
    h[j] = hh;
    l[j] = f2bf(v - bf2f(hh));
  }
  *(s16x8*)&hi[(size_t)col * KP + k8] = h;
  *(s16x8*)&lo[(size_t)col * KP + k8] = l;
}

// ---------------------------------------------------------------- MFMA GEMM
// C[M,N] = A[M,KP] @ Bt[N,KP]^T, split-bf16 (hi/lo, 3 products ~ fp32 precision).
// Inputs pre-converted bf16 hi/lo (zero-padded K). Tile 128x128, BK=32, 256 thr
// = 4 waves (2x2 of 64x64). LDS rows padded to 40 shorts (80 B): b128 reads land
// 2 lanes/bank = free (m136). 40 KB LDS -> 4 blocks/CU.
// EPI: 0 none, 1 bias+relu, 2 bias. OUTF32: 1 -> f32 C; 0 -> bf16 hi/lo C.
#define LDSW 40

template <int EPI, int OUTF32>
__global__ __launch_bounds__(256, 4) void mfma_gemm(
    const short* __restrict__ Ah, const short* __restrict__ Al,
    const short* __restrict__ Bh, const short* __restrict__ Bl,
    const float* __restrict__ bias,
    float* __restrict__ C, short* __restrict__ Ch, short* __restrict__ Cl,
    int M, int N, int KP, int gn) {
  __shared__ short sAh[128 * LDSW], sAl[128 * LDSW];
  __shared__ short sBh[128 * LDSW], sBl[128 * LDSW];
  int tid = threadIdx.x;

  int wgid = xcd_swizzle(blockIdx.x, gridDim.x);
  int rb = wgid / gn;          // row block (col-fastest within XCD chunk)
  int cb = wgid - rb * gn;
  int m0 = rb * 128;
  int n0 = cb * 128;

  int lane = tid & 63, wv = tid >> 6;
  int wm = wv >> 1, wn = wv & 1;      // 2x2 wave grid, each 64x64
  int lrow = lane & 15, lblk = lane >> 4;

  int srow = tid >> 2;   // staging: rows 0..63 (+64 on 2nd iter)
  int sslot = tid & 3;   // 16B slot (8 shorts)

  f32x4 acc[4][4] = {};

  for (int k0 = 0; k0 < KP; k0 += 32) {
    __syncthreads();  // previous iter's reads done before overwrite
#pragma unroll
    for (int i = 0; i < 2; ++i) {
      int row = srow + i * 64;
      int lds = row * LDSW + sslot * 8;
      size_t ga = (size_t)(m0 + row) * KP + k0 + sslot * 8;
      s16x8 vh = {}, vl = {};
      if (m0 + row < M) { vh = *(const s16x8*)&Ah[ga]; vl = *(const s16x8*)&Al[ga]; }
      *(s16x8*)&sAh[lds] = vh;
      *(s16x8*)&sAl[lds] = vl;
      size_t gb = (size_t)(n0 + row) * KP + k0 + sslot * 8;
      *(s16x8*)&sBh[lds] = *(const s16x8*)&Bh[gb];
      *(s16x8*)&sBl[lds] = *(const s16x8*)&Bl[gb];
    }
    __syncthreads();
    s16x8 ah[4], al[4];
#pragma unroll
    for (int f = 0; f < 4; ++f) {
      int o = (wm * 64 + f * 16 + lrow) * LDSW + lblk * 8;
      ah[f] = *(const s16x8*)&sAh[o];
      al[f] = *(const s16x8*)&sAl[o];
    }
#pragma unroll
    for (int j = 0; j < 4; ++j) {
      int o = (wn * 64 + j * 16 + lrow) * LDSW + lblk * 8;
      s16x8 bh = *(const s16x8*)&sBh[o];
      s16x8 bl = *(const s16x8*)&sBl[o];
#pragma unroll
      for (int i = 0; i < 4; ++i) {
        acc[i][j] = __builtin_amdgcn_mfma_f32_16x16x32_bf16(ah[i], bh, acc[i][j], 0, 0, 0);
        acc[i][j] = __builtin_amdgcn_mfma_f32_16x16x32_bf16(ah[i], bl, acc[i][j], 0, 0, 0);
        acc[i][j] = __builtin_amdgcn_mfma_f32_16x16x32_bf16(al[i], bh, acc[i][j], 0, 0, 0);
      }
    }
  }

  // epilogue: C/D layout col=lane&15, row=(lane>>4)*4+reg [m89]
#pragma unroll
  for (int i = 0; i < 4; ++i) {
    int crow0 = m0 + wm * 64 + i * 16 + lblk * 4;
#pragma unroll
    for (int j = 0; j < 4; ++j) {
      int ccol = n0 + wn * 64 + j * 16 + lrow;
      float bb = EPI ? bias[ccol] : 0.f;
#pragma unroll
      for (int r = 0; r < 4; ++r) {
        int crow = crow0 + r;
        if (crow >= M) continue;
        float v = acc[i][j][r] + bb;
        if (EPI == 1) v = fmaxf(v, 0.f);
        if (OUTF32) {
          C[(size_t)crow * N + ccol] = v;
        } else {
          short hh = f2bf(v);
          Ch[(size_t)crow * N + ccol] = hh;
          Cl[(size_t)crow * N + ccol] = f2bf(v - bf2f(hh));
        }
      }
    }
  }
}

// ---------------------------------------------------------------- aggregation
// oh/ol[n,:] = split_bf16(relu(dinv[n]*sum_{s in nbrs(n)} dinv[s]*xw[s,:] + bias))
// float4 per lane (16B gather granularity); C/4 lanes per node.
template <int C>
__global__ __launch_bounds__(256) void agg_kernel(const float* __restrict__ xw,
                                                  const int* __restrict__ offs,
                                                  const int* __restrict__ csr,
                                                  const float* __restrict__ dinv,
                                                  const float* __restrict__ bias,
                                                  short* __restrict__ oh,
                                                  short* __restrict__ ol) {
  constexpr int TPN = C / 4;       // threads per node (64 or 32)
  constexpr int NPB = 256 / TPN;   // nodes per block (4 or 8)
  int lane = threadIdx.x % TPN;
  int sub  = threadIdx.x / TPN;
  int node = blockIdx.x * NPB + sub;
  if (node >= NN) return;

  const float4* xw4 = (const float4*)xw;
  int beg = offs[node], end = offs[node + 1];
  float4 acc = make_float4(0.f, 0.f, 0.f, 0.f);
  int j = beg;
  for (; j + 2 <= end; j += 2) {
    int s0 = csr[j], s1 = csr[j + 1];
    float d0 = dinv[s0], d1 = dinv[s1];
    float4 v0 = xw4[(size_t)s0 * TPN + lane];
    float4 v1 = xw4[(size_t)s1 * TPN + lane];
    acc.x += d0 * v0.x + d1 * v1.x;
    acc.y += d0 * v0.y + d1 * v1.y;
    acc.z += d0 * v0.z + d1 * v1.z;
    acc.w += d0 * v0.w + d1 * v1.w;
  }
  if (j < end) {
    int s = csr[j];
    float d = dinv[s];
    float4 v = xw4[(size_t)s * TPN + lane];
    acc.x += d * v.x; acc.y += d * v.y; acc.z += d * v.z; acc.w += d * v.w;
  }
  float dn = dinv[node];
  float4 b = ((const float4*)bias)[lane];
  float o[4];
  o[0] = fmaxf(dn * acc.x + b.x, 0.f);
  o[1] = fmaxf(dn * acc.y + b.y, 0.f);
  o[2] = fmaxf(dn * acc.z + b.z, 0.f);
  o[3] = fmaxf(dn * acc.w + b.w, 0.f);
  s16x4 h, l;
#pragma unroll
  for (int q = 0; q < 4; ++q) {
    short hh = f2bf(o[q]);
    h[q] = hh;
    l[q] = f2bf(o[q] - bf2f(hh));
  }
  *(s16x4*)&oh[(size_t)node * C + lane * 4] = h;
  *(s16x4*)&ol[(size_t)node * C + lane * 4] = l;
}

// ---------------------------------------------------------------- row L2 norm
__global__ __launch_bounds__(128) void rownorm_kernel(const float* __restrict__ zi,
                                                      float* __restrict__ z) {
  int row = blockIdx.x;
  int t = threadIdx.x;
  float v = zi[(size_t)row * 128 + t];
  float ss = wave_sum(v * v);
  __shared__ float wsum[2];
  if ((t & 63) == 0) wsum[t >> 6] = ss;
  __syncthreads();
  float tot = wsum[0] + wsum[1];
  float rinv = 1.f / fmaxf(sqrtf(tot), 1e-12f);
  z[(size_t)row * 128 + t] = v * rinv;
}

// ---------------------------------------------------------------- classifier head
// out[row, 0..9] = softmax((hi+lo)[row,0..511] @ W[512,10] + bias)
__global__ __launch_bounds__(256) void cls_kernel(const short* __restrict__ c1h,
                                                  const short* __restrict__ c1l,
                                                  const float* __restrict__ W,
                                                  const float* __restrict__ bias,
                                                  float* __restrict__ out, int M) {
  __shared__ float Wt[10 * 512];  // transposed: Wt[c*512 + k]
  int tid = threadIdx.x;
  for (int i = tid; i < 5120; i += 256) Wt[i] = W[(i & 511) * 10 + (i >> 9)];
  __syncthreads();
  int wave = tid >> 6, lane = tid & 63;
  int row0 = blockIdx.x * 16 + wave * 4;
  int k8 = lane * 8;  // each lane covers 8 consecutive k
#pragma unroll 1
  for (int r = 0; r < 4; ++r) {
    int row = row0 + r;
    if (row >= M) continue;
    float acc[10] = {};
    s16x8 xh = *(const s16x8*)&c1h[(size_t)row * 512 + k8];
    s16x8 xl = *(const s16x8*)&c1l[(size_t)row * 512 + k8];
#pragma unroll
    for (int j = 0; j < 8; ++j) {
      float xv = bf2f(xh[j]) + bf2f(xl[j]);
#pragma unroll
      for (int c = 0; c < 10; ++c) acc[c] += xv * Wt[c * 512 + k8 + j];
    }
#pragma unroll
    for (int c = 0; c < 10; ++c) acc[c] = wave_sum(acc[c]);
    float mx = -1e30f;
#pragma unroll
    for (int c = 0; c < 10; ++c) { acc[c] += bias[c]; mx = fmaxf(mx, acc[c]); }
    float sum = 0.f;
#pragma unroll
    for (int c = 0; c < 10; ++c) { acc[c] = expf(acc[c] - mx); sum += acc[c]; }
    float rs = 1.f / sum;
    if (lane < 10) out[(size_t)row * 10 + lane] = acc[lane] * rs;
  }
}

// ---------------------------------------------------------------- launch
extern "C" void kernel_launch(void* const* d_in, const int* in_sizes, int n_in,
                              void* d_out, int out_size, void* d_ws, size_t ws_size,
                              hipStream_t stream) {
  const float* x   = (const float*)d_in[0];
  const int*   ei  = (const int*)d_in[1];
  const float* W1  = (const float*)d_in[2];
  const float* b1  = (const float*)d_in[3];
  const float* W2  = (const float*)d_in[4];
  const float* b2  = (const float*)d_in[5];
  const float* Wi1 = (const float*)d_in[6];
  const float* bi1 = (const float*)d_in[7];
  const float* Wi2 = (const float*)d_in[8];
  const float* bi2 = (const float*)d_in[9];
  const float* Wc1 = (const float*)d_in[10];
  const float* bc1 = (const float*)d_in[11];
  const float* Wc2 = (const float*)d_in[12];
  const float* bc2 = (const float*)d_in[13];

  float* out_z = (float*)d_out;                      // [50000,128]
  float* out_c = (float*)d_out + (size_t)NN * 128;   // [50000,10]

  // workspace layout (aliased, strictly sequential lifetimes) ~210 MB
  char* ws = (char*)d_ws;
  size_t off = 0;
  auto alloc = [&](size_t bytes) {
    size_t r = off;
    off = (off + bytes + 255) & ~(size_t)255;
    return r;
  };
  int*   deg    = (int*)(ws + alloc((size_t)NN * 4));
  int*   cursor = (int*)(ws + alloc((size_t)NN * 4));
  int*   offs   = (int*)(ws + alloc((size_t)(NN + 1) * 4));
  float* dinv   = (float*)(ws + alloc((size_t)NN * 4));
  int*   csr    = (int*)(ws + alloc((size_t)(NE + NN) * 4));
  // transposed weight hi/lo buffers (small)
  short* W1th  = (short*)(ws + alloc((size_t)256 * 512 * 2));
  short* W1tl  = (short*)(ws + alloc((size_t)256 * 512 * 2));
  short* W2th  = (short*)(ws + alloc((size_t)128 * 256 * 2));
  short* W2tl  = (short*)(ws + alloc((size_t)128 * 256 * 2));
  short* Wi1th = (short*)(ws + alloc((size_t)512 * 128 * 2));
  short* Wi1tl = (short*)(ws + alloc((size_t)512 * 128 * 2));
  short* Wi2th = (short*)(ws + alloc((size_t)128 * 512 * 2));
  short* Wi2tl = (short*)(ws + alloc((size_t)128 * 512 * 2));
  short* Wc1th = (short*)(ws + alloc((size_t)512 * 128 * 2));
  short* Wc1tl = (short*)(ws + alloc((size_t)512 * 128 * 2));
  // big buffers
  float* bufA = (float*)(ws + alloc((size_t)NN * 256 * 4));        // xw -> hw2 -> zi (f32)
  short* h1h  = (short*)(ws + alloc((size_t)NN * 256 * 2));        // h1 hi (dies after GEMM2)
  short* h1l  = (short*)(ws + alloc((size_t)NN * 256 * 2));        // h1 lo
  short* Dh   = (short*)(ws + alloc((size_t)NN * 512 * 2));        // x-hi -> zi1-hi -> c1-hi
  short* Dl   = (short*)(ws + alloc((size_t)NN * 512 * 2));        // x-lo -> zi1-lo -> c1-lo
  short* h2h  = h1h;                                               // alias: h1 dead when h2 born
  short* h2l  = h1l;
  (void)ws_size; (void)in_sizes; (void)n_in; (void)out_size;

  const int M = NN;
  const int gmb = (M + 127) / 128;  // 391 row blocks
  dim3 blk(256);

  // graph prep
  init_kernel<<<(NN + 255) / 256, 256, 0, stream>>>(deg, cursor, NN);
  deg_kernel<<<(NE + 255) / 256, 256, 0, stream>>>(ei, deg);
  dinv_kernel<<<(NN + 255) / 256, 256, 0, stream>>>(deg, dinv, NN);
  scan_kernel<<<1, 256, 0, stream>>>(deg, offs, NN);
  scatter_kernel<<<(NE + NN + 255) / 256, 256, 0, stream>>>(ei, offs, cursor, csr);

  // pre-convert inputs (x zero-padded K 500->512) and weights (transposed)
  convert_a<<<(M * (512 / 8) + 255) / 256, 256, 0, stream>>>(x, Dh, Dl, M, 500, 512);
  convert_w<<<(256 * (512 / 8) + 255) / 256, 256, 0, stream>>>(W1, W1th, W1tl, 500, 256, 512);
  convert_w<<<(128 * (256 / 8) + 255) / 256, 256, 0, stream>>>(W2, W2th, W2tl, 256, 128, 256);
  convert_w<<<(512 * (128 / 8) + 255) / 256, 256, 0, stream>>>(Wi1, Wi1th, Wi1tl, 128, 512, 128);
  convert_w<<<(128 * (512 / 8) + 255) / 256, 256, 0, stream>>>(Wi2, Wi2th, Wi2tl, 512, 128, 512);
  convert_w<<<(512 * (128 / 8) + 255) / 256, 256, 0, stream>>>(Wc1, Wc1th, Wc1tl, 128, 512, 128);

  // layer 1: xw = x @ W1   [M,512p]@[512p,256] -> f32 bufA
  mfma_gemm<0, 1><<<gmb * 2, blk, 0, stream>>>(Dh, Dl, W1th, W1tl, nullptr,
                                               bufA, nullptr, nullptr, M, 256, 512, 2);
  agg_kernel<256><<<(NN + 3) / 4, 256, 0, stream>>>(bufA, offs, csr, dinv, b1, h1h, h1l);
  // layer 2: hw2 = h1 @ W2   [M,256]@[256,128] -> f32 bufA
  mfma_gemm<0, 1><<<gmb * 1, blk, 0, stream>>>(h1h, h1l, W2th, W2tl, nullptr,
                                               bufA, nullptr, nullptr, M, 128, 256, 1);
  agg_kernel<128><<<(NN + 7) / 8, 256, 0, stream>>>(bufA, offs, csr, dinv, b2, h2h, h2l);
  // instance head: zi1 = relu(h2@Wi1+bi1) -> hilo D; zi = zi1@Wi2+bi2 -> f32 bufA
  mfma_gemm<1, 0><<<gmb * 4, blk, 0, stream>>>(h2h, h2l, Wi1th, Wi1tl, bi1,
                                               nullptr, Dh, Dl, M, 512, 128, 4);
  mfma_gemm<2, 1><<<gmb * 1, blk, 0, stream>>>(Dh, Dl, Wi2th, Wi2tl, bi2,
                                               bufA, nullptr, nullptr, M, 128, 512, 1);
  rownorm_kernel<<<M, 128, 0, stream>>>(bufA, out_z);
  // class head: c1 = relu(h2@Wc1+bc1) -> hilo D; c = softmax(c1@Wc2+bc2)
  mfma_gemm<1, 0><<<gmb * 4, blk, 0, stream>>>(h2h, h2l, Wc1th, Wc1tl, bc1,
                                               nullptr, Dh, Dl, M, 512, 128, 4);
  cls_kernel<<<(M + 15) / 16, 256, 0, stream>>>(Dh, Dl, Wc2, bc2, out_c, M);
}

// Round 8
// 825.992 us; speedup vs baseline: 1.3394x; 1.0067x over previous
//
#include <hip/hip_runtime.h>
#include <math.h>

#define NN 50000
#define NE 800000

typedef __attribute__((ext_vector_type(4))) float f32x4;
typedef __attribute__((ext_vector_type(8))) short s16x8;
typedef __attribute__((ext_vector_type(4))) short s16x4;

// ---------------------------------------------------------------- utilities
__device__ inline float wave_sum(float v) {
#pragma unroll
  for (int off = 32; off >= 1; off >>= 1) v += __shfl_xor(v, off, 64);
  return v;
}

// bijective XCD-chunked swizzle (m204): consecutive wgids within one XCD
__device__ inline int xcd_swizzle(int orig, int nwg) {
  int q = nwg >> 3, r = nwg & 7;
  int xcd = orig & 7, pos = orig >> 3;
  return (xcd < r ? xcd * (q + 1) : r * (q + 1) + (xcd - r) * q) + pos;
}

// fp32 -> bf16 RNE, and bf16 -> fp32
__device__ inline short f2bf(float f) {
  unsigned u = __float_as_uint(f);
  unsigned r = (u + 0x7fffu + ((u >> 16) & 1u)) >> 16;
  return (short)r;
}
__device__ inline float bf2f(short h) {
  return __uint_as_float(((unsigned)(unsigned short)h) << 16);
}

// ---------------------------------------------------------------- graph prep
__global__ __launch_bounds__(256) void init_kernel(int* __restrict__ deg,
                                                   int* __restrict__ cursor, int n) {
  int i = blockIdx.x * 256 + threadIdx.x;
  if (i < n) { deg[i] = 1; cursor[i] = 0; }  // deg starts at 1 (self-loop)
}

__global__ __launch_bounds__(256) void deg_kernel(const int* __restrict__ ei,
                                                  int* __restrict__ deg) {
  int e = blockIdx.x * 256 + threadIdx.x;
  if (e < NE) atomicAdd(&deg[ei[NE + e]], 1);  // dst row of edge_index
}

__global__ __launch_bounds__(256) void dinv_kernel(const int* __restrict__ deg,
                                                   float* __restrict__ dinv, int n) {
  int i = blockIdx.x * 256 + threadIdx.x;
  if (i < n) dinv[i] = rsqrtf((float)deg[i]);  // deg >= 1 always
}

// single-block exclusive scan of deg -> offs[0..n], offs[n] = total
__global__ __launch_bounds__(256) void scan_kernel(const int* __restrict__ cnt,
                                                   int* __restrict__ offs, int n) {
  __shared__ int buf0[256], buf1[256];
  int tid = threadIdx.x;
  int per = (n + 255) >> 8;
  int start = tid * per;
  int end = min(start + per, n);
  int s = 0;
  for (int i = start; i < end; ++i) s += cnt[i];
  buf0[tid] = s;
  __syncthreads();
  int* src = buf0;
  int* dst = buf1;
#pragma unroll
  for (int off = 1; off < 256; off <<= 1) {
    int v = src[tid];
    if (tid >= off) v += src[tid - off];
    dst[tid] = v;
    __syncthreads();
    int* t = src; src = dst; dst = t;
  }
  int run = (tid == 0) ? 0 : src[tid - 1];
  for (int i = start; i < end; ++i) { offs[i] = run; run += cnt[i]; }
  if (end == n) offs[n] = run;
}

__global__ __launch_bounds__(256) void scatter_kernel(const int* __restrict__ ei,
                                                      const int* __restrict__ offs,
                                                      int* __restrict__ cursor,
                                                      int* __restrict__ csr) {
  int e = blockIdx.x * 256 + threadIdx.x;
  if (e >= NE + NN) return;
  int s, d;
  if (e < NE) { s = ei[e]; d = ei[NE + e]; }
  else        { s = e - NE; d = s; }           // self-loops
  int pos = atomicAdd(&cursor[d], 1);
  csr[offs[d] + pos] = s;
}

// ---------------------------------------------------------------- converters
// f32 [M][K] row-major -> bf16 hi/lo [M][KP], zero-padded to KP (KP%8==0)
__global__ __launch_bounds__(256) void convert_a(const float* __restrict__ in,
                                                 short* __restrict__ hi,
                                                 short* __restrict__ lo,
                                                 int M, int K, int KP) {
  int t = blockIdx.x * 256 + threadIdx.x;
  int perRow = KP >> 3;
  int row = t / perRow;
  if (row >= M) return;
  int k8 = (t - row * perRow) << 3;
  s16x8 h, l;
#pragma unroll
  for (int j = 0; j < 8; ++j) {
    int k = k8 + j;
    float v = (k < K) ? in[(size_t)row * K + k] : 0.f;
    short hh = f2bf(v);
    h[j] = hh;
    l[j] = f2bf(v - bf2f(hh));
  }
  *(s16x8*)&hi[(size_t)row * KP + k8] = h;
  *(s16x8*)&lo[(size_t)row * KP + k8] = l;
}

// weight f32 [K][N] -> TRANSPOSED bf16 hi/lo [N][KP], zero-padded
__global__ __launch_bounds__(256) void convert_w(const float* __restrict__ B,
                                                 short* __restrict__ hi,
                                                 short* __restrict__ lo,
                                                 int K, int N, int KP) {
  int t = blockIdx.x * 256 + threadIdx.x;
  int perRow = KP >> 3;
  int col = t / perRow;
  if (col >= N) return;
  int k8 = (t - col * perRow) << 3;
  s16x8 h, l;
#pragma unroll
  for (int j = 0; j < 8; ++j) {
    int k = k8 + j;
    float v = (k < K) ? B[(size_t)k * N + col] : 0.f;
    short hh = f2bf(v);
    h[j] = hh;
    l[j] = f2bf(v - bf2f(hh));
  }
  *(s16x8*)&hi[(size_t)col * KP + k8] = h;
  *(s16x8*)&lo[(size_t)col * KP + k8] = l;
}

// ---------------------------------------------------------------- MFMA GEMM
// C[M,N] = A[M,KP] @ Bt[N,KP]^T, split-bf16 (hi/lo, 3 products ~ fp32 precision).
// 2-phase reg-staged pipeline (T14/T3-minimum): tile t+1's global loads are
// issued right after tile t's ds_writes, so HBM latency hides under tile t's
// ds_read+MFMA compute. Tile 128x128, BK=32, 256 thr = 4 waves (2x2 of 64x64).
// LDS rows 40 shorts (80 B): b128 frag reads hit the uniform 8-lanes-per-quad
// floor. 40 KB LDS; __launch_bounds__(256,3) -> VGPR cap 170, 3 blocks/CU.
// EPI: 0 none, 1 bias+relu, 2 bias. OUTF32: 1 -> f32 C; 0 -> bf16 hi/lo C.
#define LDSW 40

template <int EPI, int OUTF32>
__global__ __launch_bounds__(256, 3) void mfma_gemm(
    const short* __restrict__ Ah, const short* __restrict__ Al,
    const short* __restrict__ Bh, const short* __restrict__ Bl,
    const float* __restrict__ bias,
    float* __restrict__ C, short* __restrict__ Ch, short* __restrict__ Cl,
    int M, int N, int KP, int gn) {
  __shared__ short sAh[128 * LDSW], sAl[128 * LDSW];
  __shared__ short sBh[128 * LDSW], sBl[128 * LDSW];
  int tid = threadIdx.x;

  int wgid = xcd_swizzle(blockIdx.x, gridDim.x);
  int rb = wgid / gn;          // row block (col-fastest within XCD chunk)
  int cb = wgid - rb * gn;
  int m0 = rb * 128;
  int n0 = cb * 128;

  int lane = tid & 63, wv = tid >> 6;
  int wm = wv >> 1, wn = wv & 1;      // 2x2 wave grid, each 64x64
  int lrow = lane & 15, lblk = lane >> 4;

  int srow = tid >> 2;   // staging rows: srow and srow+64
  int sslot = tid & 3;   // 16B slot (8 shorts)
  const int g0ok = (m0 + srow < M);
  const int g1ok = (m0 + srow + 64 < M);

  f32x4 acc[4][4] = {};
  s16x8 rA0h, rA0l, rA1h, rA1l, rB0h, rB0l, rB1h, rB1l;  // staging regs

  auto load_tile = [&](int k0) {
    size_t a0 = (size_t)(m0 + srow) * KP + k0 + sslot * 8;
    size_t a1 = a0 + (size_t)64 * KP;
    size_t b0 = (size_t)(n0 + srow) * KP + k0 + sslot * 8;
    size_t b1 = b0 + (size_t)64 * KP;
    rA0h = g0ok ? *(const s16x8*)&Ah[a0] : (s16x8){};
    rA0l = g0ok ? *(const s16x8*)&Al[a0] : (s16x8){};
    rA1h = g1ok ? *(const s16x8*)&Ah[a1] : (s16x8){};
    rA1l = g1ok ? *(const s16x8*)&Al[a1] : (s16x8){};
    rB0h = *(const s16x8*)&Bh[b0];
    rB0l = *(const s16x8*)&Bl[b0];
    rB1h = *(const s16x8*)&Bh[b1];
    rB1l = *(const s16x8*)&Bl[b1];
  };

  load_tile(0);  // prologue prefetch
  int nt = KP >> 5;
  for (int t = 0; t < nt; ++t) {
    __syncthreads();  // all waves done reading previous tile
    int l0 = srow * LDSW + sslot * 8;
    int l1 = l0 + 64 * LDSW;
    *(s16x8*)&sAh[l0] = rA0h;
    *(s16x8*)&sAl[l0] = rA0l;
    *(s16x8*)&sAh[l1] = rA1h;
    *(s16x8*)&sAl[l1] = rA1l;
    *(s16x8*)&sBh[l0] = rB0h;
    *(s16x8*)&sBl[l0] = rB0l;
    *(s16x8*)&sBh[l1] = rB1h;
    *(s16x8*)&sBl[l1] = rB1l;
    if (t + 1 < nt) load_tile((t + 1) << 5);  // in flight during compute below
    __syncthreads();  // tile t visible
    s16x8 ah[4], al[4];
#pragma unroll
    for (int f = 0; f < 4; ++f) {
      int o = (wm * 64 + f * 16 + lrow) * LDSW + lblk * 8;
      ah[f] = *(const s16x8*)&sAh[o];
      al[f] = *(const s16x8*)&sAl[o];
    }
#pragma unroll
    for (int j = 0; j < 4; ++j) {
      int o = (wn * 64 + j * 16 + lrow) * LDSW + lblk * 8;
      s16x8 bh = *(const s16x8*)&sBh[o];
      s16x8 bl = *(const s16x8*)&sBl[o];
#pragma unroll
      for (int i = 0; i < 4; ++i) {
        acc[i][j] = __builtin_amdgcn_mfma_f32_16x16x32_bf16(ah[i], bh, acc[i][j], 0, 0, 0);
        acc[i][j] = __builtin_amdgcn_mfma_f32_16x16x32_bf16(ah[i], bl, acc[i][j], 0, 0, 0);
        acc[i][j] = __builtin_amdgcn_mfma_f32_16x16x32_bf16(al[i], bh, acc[i][j], 0, 0, 0);
      }
    }
  }

  // epilogue: C/D layout col=lane&15, row=(lane>>4)*4+reg [m89]
#pragma unroll
  for (int i = 0; i < 4; ++i) {
    int crow0 = m0 + wm * 64 + i * 16 + (lane >> 4) * 4;
#pragma unroll
    for (int j = 0; j < 4; ++j) {
      int ccol = n0 + wn * 64 + j * 16 + lrow;
      float bb = EPI ? bias[ccol] : 0.f;
#pragma unroll
      for (int r = 0; r < 4; ++r) {
        int crow = crow0 + r;
        if (crow >= M) continue;
        float v = acc[i][j][r] + bb;
        if (EPI == 1) v = fmaxf(v, 0.f);
        if (OUTF32) {
          C[(size_t)crow * N + ccol] = v;
        } else {
          short hh = f2bf(v);
          Ch[(size_t)crow * N + ccol] = hh;
          Cl[(size_t)crow * N + ccol] = f2bf(v - bf2f(hh));
        }
      }
    }
  }
}

// ---------------------------------------------------------------- aggregation
// oh/ol[n,:] = split_bf16(relu(dinv[n]*sum_{s in nbrs(n)} dinv[s]*xw[s,:] + bias))
// float4 per lane (16B gather granularity); C/4 lanes per node.
template <int C>
__global__ __launch_bounds__(256) void agg_kernel(const float* __restrict__ xw,
                                                  const int* __restrict__ offs,
                                                  const int* __restrict__ csr,
                                                  const float* __restrict__ dinv,
                                                  const float* __restrict__ bias,
                                                  short* __restrict__ oh,
                                                  short* __restrict__ ol) {
  constexpr int TPN = C / 4;       // threads per node (64 or 32)
  constexpr int NPB = 256 / TPN;   // nodes per block (4 or 8)
  int lane = threadIdx.x % TPN;
  int sub  = threadIdx.x / TPN;
  int node = blockIdx.x * NPB + sub;
  if (node >= NN) return;

  const float4* xw4 = (const float4*)xw;
  int beg = offs[node], end = offs[node + 1];
  float4 acc = make_float4(0.f, 0.f, 0.f, 0.f);
  int j = beg;
  for (; j + 2 <= end; j += 2) {
    int s0 = csr[j], s1 = csr[j + 1];
    float d0 = dinv[s0], d1 = dinv[s1];
    float4 v0 = xw4[(size_t)s0 * TPN + lane];
    float4 v1 = xw4[(size_t)s1 * TPN + lane];
    acc.x += d0 * v0.x + d1 * v1.x;
    acc.y += d0 * v0.y + d1 * v1.y;
    acc.z += d0 * v0.z + d1 * v1.z;
    acc.w += d0 * v0.w + d1 * v1.w;
  }
  if (j < end) {
    int s = csr[j];
    float d = dinv[s];
    float4 v = xw4[(size_t)s * TPN + lane];
    acc.x += d * v.x; acc.y += d * v.y; acc.z += d * v.z; acc.w += d * v.w;
  }
  float dn = dinv[node];
  float4 b = ((const float4*)bias)[lane];
  float o[4];
  o[0] = fmaxf(dn * acc.x + b.x, 0.f);
  o[1] = fmaxf(dn * acc.y + b.y, 0.f);
  o[2] = fmaxf(dn * acc.z + b.z, 0.f);
  o[3] = fmaxf(dn * acc.w + b.w, 0.f);
  s16x4 h, l;
#pragma unroll
  for (int q = 0; q < 4; ++q) {
    short hh = f2bf(o[q]);
    h[q] = hh;
    l[q] = f2bf(o[q] - bf2f(hh));
  }
  *(s16x4*)&oh[(size_t)node * C + lane * 4] = h;
  *(s16x4*)&ol[(size_t)node * C + lane * 4] = l;
}

// ---------------------------------------------------------------- row L2 norm
__global__ __launch_bounds__(128) void rownorm_kernel(const float* __restrict__ zi,
                                                      float* __restrict__ z) {
  int row = blockIdx.x;
  int t = threadIdx.x;
  float v = zi[(size_t)row * 128 + t];
  float ss = wave_sum(v * v);
  __shared__ float wsum[2];
  if ((t & 63) == 0) wsum[t >> 6] = ss;
  __syncthreads();
  float tot = wsum[0] + wsum[1];
  float rinv = 1.f / fmaxf(sqrtf(tot), 1e-12f);
  z[(size_t)row * 128 + t] = v * rinv;
}

// ---------------------------------------------------------------- classifier head
// out[row, 0..9] = softmax((hi+lo)[row,0..511] @ W[512,10] + bias)
__global__ __launch_bounds__(256) void cls_kernel(const short* __restrict__ c1h,
                                                  const short* __restrict__ c1l,
                                                  const float* __restrict__ W,
                                                  const float* __restrict__ bias,
                                                  float* __restrict__ out, int M) {
  __shared__ float Wt[10 * 512];  // transposed: Wt[c*512 + k]
  int tid = threadIdx.x;
  for (int i = tid; i < 5120; i += 256) Wt[i] = W[(i & 511) * 10 + (i >> 9)];
  __syncthreads();
  int wave = tid >> 6, lane = tid & 63;
  int row0 = blockIdx.x * 16 + wave * 4;
  int k8 = lane * 8;  // each lane covers 8 consecutive k
#pragma unroll 1
  for (int r = 0; r < 4; ++r) {
    int row = row0 + r;
    if (row >= M) continue;
    float acc[10] = {};
    s16x8 xh = *(const s16x8*)&c1h[(size_t)row * 512 + k8];
    s16x8 xl = *(const s16x8*)&c1l[(size_t)row * 512 + k8];
#pragma unroll
    for (int j = 0; j < 8; ++j) {
      float xv = bf2f(xh[j]) + bf2f(xl[j]);
#pragma unroll
      for (int c = 0; c < 10; ++c) acc[c] += xv * Wt[c * 512 + k8 + j];
    }
#pragma unroll
    for (int c = 0; c < 10; ++c) acc[c] = wave_sum(acc[c]);
    float mx = -1e30f;
#pragma unroll
    for (int c = 0; c < 10; ++c) { acc[c] += bias[c]; mx = fmaxf(mx, acc[c]); }
    float sum = 0.f;
#pragma unroll
    for (int c = 0; c < 10; ++c) { acc[c] = expf(acc[c] - mx); sum += acc[c]; }
    float rs = 1.f / sum;
    if (lane < 10) out[(size_t)row * 10 + lane] = acc[lane] * rs;
  }
}

// ---------------------------------------------------------------- launch
extern "C" void kernel_launch(void* const* d_in, const int* in_sizes, int n_in,
                              void* d_out, int out_size, void* d_ws, size_t ws_size,
                              hipStream_t stream) {
  const float* x   = (const float*)d_in[0];
  const int*   ei  = (const int*)d_in[1];
  const float* W1  = (const float*)d_in[2];
  const float* b1  = (const float*)d_in[3];
  const float* W2  = (const float*)d_in[4];
  const float* b2  = (const float*)d_in[5];
  const float* Wi1 = (const float*)d_in[6];
  const float* bi1 = (const float*)d_in[7];
  const float* Wi2 = (const float*)d_in[8];
  const float* bi2 = (const float*)d_in[9];
  const float* Wc1 = (const float*)d_in[10];
  const float* bc1 = (const float*)d_in[11];
  const float* Wc2 = (const float*)d_in[12];
  const float* bc2 = (const float*)d_in[13];

  float* out_z = (float*)d_out;                      // [50000,128]
  float* out_c = (float*)d_out + (size_t)NN * 128;   // [50000,10]

  // workspace layout (aliased, strictly sequential lifetimes) ~210 MB
  char* ws = (char*)d_ws;
  size_t off = 0;
  auto alloc = [&](size_t bytes) {
    size_t r = off;
    off = (off + bytes + 255) & ~(size_t)255;
    return r;
  };
  int*   deg    = (int*)(ws + alloc((size_t)NN * 4));
  int*   cursor = (int*)(ws + alloc((size_t)NN * 4));
  int*   offs   = (int*)(ws + alloc((size_t)(NN + 1) * 4));
  float* dinv   = (float*)(ws + alloc((size_t)NN * 4));
  int*   csr    = (int*)(ws + alloc((size_t)(NE + NN) * 4));
  // transposed weight hi/lo buffers (small)
  short* W1th  = (short*)(ws + alloc((size_t)256 * 512 * 2));
  short* W1tl  = (short*)(ws + alloc((size_t)256 * 512 * 2));
  short* W2th  = (short*)(ws + alloc((size_t)128 * 256 * 2));
  short* W2tl  = (short*)(ws + alloc((size_t)128 * 256 * 2));
  short* Wi1th = (short*)(ws + alloc((size_t)512 * 128 * 2));
  short* Wi1tl = (short*)(ws + alloc((size_t)512 * 128 * 2));
  short* Wi2th = (short*)(ws + alloc((size_t)128 * 512 * 2));
  short* Wi2tl = (short*)(ws + alloc((size_t)128 * 512 * 2));
  short* Wc1th = (short*)(ws + alloc((size_t)512 * 128 * 2));
  short* Wc1tl = (short*)(ws + alloc((size_t)512 * 128 * 2));
  // big buffers
  float* bufA = (float*)(ws + alloc((size_t)NN * 256 * 4));        // xw -> hw2 -> zi (f32)
  short* h1h  = (short*)(ws + alloc((size_t)NN * 256 * 2));        // h1 hi (dies after GEMM2)
  short* h1l  = (short*)(ws + alloc((size_t)NN * 256 * 2));        // h1 lo
  short* Dh   = (short*)(ws + alloc((size_t)NN * 512 * 2));        // x-hi -> zi1-hi -> c1-hi
  short* Dl   = (short*)(ws + alloc((size_t)NN * 512 * 2));        // x-lo -> zi1-lo -> c1-lo
  short* h2h  = h1h;                                               // alias: h1 dead when h2 born
  short* h2l  = h1l;
  (void)ws_size; (void)in_sizes; (void)n_in; (void)out_size;

  const int M = NN;
  const int gmb = (M + 127) / 128;  // 391 row blocks
  dim3 blk(256);

  // graph prep
  init_kernel<<<(NN + 255) / 256, 256, 0, stream>>>(deg, cursor, NN);
  deg_kernel<<<(NE + 255) / 256, 256, 0, stream>>>(ei, deg);
  dinv_kernel<<<(NN + 255) / 256, 256, 0, stream>>>(deg, dinv, NN);
  scan_kernel<<<1, 256, 0, stream>>>(deg, offs, NN);
  scatter_kernel<<<(NE + NN + 255) / 256, 256, 0, stream>>>(ei, offs, cursor, csr);

  // pre-convert inputs (x zero-padded K 500->512) and weights (transposed)
  convert_a<<<(M * (512 / 8) + 255) / 256, 256, 0, stream>>>(x, Dh, Dl, M, 500, 512);
  convert_w<<<(256 * (512 / 8) + 255) / 256, 256, 0, stream>>>(W1, W1th, W1tl, 500, 256, 512);
  convert_w<<<(128 * (256 / 8) + 255) / 256, 256, 0, stream>>>(W2, W2th, W2tl, 256, 128, 256);
  convert_w<<<(512 * (128 / 8) + 255) / 256, 256, 0, stream>>>(Wi1, Wi1th, Wi1tl, 128, 512, 128);
  convert_w<<<(128 * (512 / 8) + 255) / 256, 256, 0, stream>>>(Wi2, Wi2th, Wi2tl, 512, 128, 512);
  convert_w<<<(512 * (128 / 8) + 255) / 256, 256, 0, stream>>>(Wc1, Wc1th, Wc1tl, 128, 512, 128);

  // layer 1: xw = x @ W1   [M,512p]@[512p,256] -> f32 bufA
  mfma_gemm<0, 1><<<gmb * 2, blk, 0, stream>>>(Dh, Dl, W1th, W1tl, nullptr,
                                               bufA, nullptr, nullptr, M, 256, 512, 2);
  agg_kernel<256><<<(NN + 3) / 4, 256, 0, stream>>>(bufA, offs, csr, dinv, b1, h1h, h1l);
  // layer 2: hw2 = h1 @ W2   [M,256]@[256,128] -> f32 bufA
  mfma_gemm<0, 1><<<gmb * 1, blk, 0, stream>>>(h1h, h1l, W2th, W2tl, nullptr,
                                               bufA, nullptr, nullptr, M, 128, 256, 1);
  agg_kernel<128><<<(NN + 7) / 8, 256, 0, stream>>>(bufA, offs, csr, dinv, b2, h2h, h2l);
  // instance head: zi1 = relu(h2@Wi1+bi1) -> hilo D; zi = zi1@Wi2+bi2 -> f32 bufA
  mfma_gemm<1, 0><<<gmb * 4, blk, 0, stream>>>(h2h, h2l, Wi1th, Wi1tl, bi1,
                                               nullptr, Dh, Dl, M, 512, 128, 4);
  mfma_gemm<2, 1><<<gmb * 1, blk, 0, stream>>>(Dh, Dl, Wi2th, Wi2tl, bi2,
                                               bufA, nullptr, nullptr, M, 128, 512, 1);
  rownorm_kernel<<<M, 128, 0, stream>>>(bufA, out_z);
  // class head: c1 = relu(h2@Wc1+bc1) -> hilo D; c = softmax(c1@Wc2+bc2)
  mfma_gemm<1, 0><<<gmb * 4, blk, 0, stream>>>(h2h, h2l, Wc1th, Wc1tl, bc1,
                                               nullptr, Dh, Dl, M, 512, 128, 4);
  cls_kernel<<<(M + 15) / 16, 256, 0, stream>>>(Dh, Dl, Wc2, bc2, out_c, M);
}